// Round 7
// baseline (2001.608 us; speedup 1.0000x reference)
//
#include <hip/hip_runtime.h>

// StructuredLSNN v7: force register residency of row[64].
// v6 post-mortem: FETCH_SIZE is KB (2.4MB, fine) — NOT spill-to-HBM. Real issue:
// VGPR_Count=84 with row[64] (+128-float staging) live -> allocator REMATERIALIZED
// row[k] as global loads from const-restrict A/enc_w at every use (48KB/block hot
// -> L1 overflow, L2 latency in the FMA chain) => ~1180 cyc/step vs ~270 floor.
// Fixes: __launch_bounds__(256,1) (allow 256 VGPR/wave; we run 1 wave/SIMD),
// asm-pin row[64] into VGPRs (blocks remat), drop consumer reg-staging (live
// temps ~8 regs; LDS float4 broadcast reads straight into the 2-way chains).
// Bit-exact orders unchanged (k-sequential single-acc FMA chains, two-rounded
// LIF update, mem*(1-spk) NaN-propagating reset).

#define TT 4096
#define NBATCH 256
#define HH 192
#define CS 64
#define NC (TT / CS)

__global__ __launch_bounds__(256, 1) void lsnn_fused(
    const float* __restrict__ x,
    const float* __restrict__ A,
    const float* __restrict__ Bv,
    const float* __restrict__ enc_w,
    const float* __restrict__ enc_b,
    const float* __restrict__ ro_w,
    const float* __restrict__ ro_b,
    float* __restrict__ out0,
    float* __restrict__ out1)
{
    __shared__ __align__(16) float st[2][CS * 64];   // chunk state tiles [q][d]
    __shared__ __align__(16) float xb[TT];           // this batch's input
    __shared__ float rate[HH];

    const int tid = threadIdx.x;
    const int b = blockIdx.x;
    const int h = tid - 64;                 // consumer lane id 0..191 (tid>=64)

    // ---- stage x[b][:] ----
    {
        const float4* xs = (const float4*)(x + (size_t)b * TT);
        float4* xd = (float4*)xb;
        for (int e = tid; e < TT / 4; e += 256) xd[e] = xs[e];
    }

    // ---- shared row registers: A row (producer wave) / enc_w row (consumers) ----
    float row[64];
    {
        const float* rsrc = (tid < 64) ? (A + (size_t)tid * 64)
                                       : (enc_w + (size_t)h * 64);
        #pragma unroll
        for (int q = 0; q < 16; ++q) {
            float4 t4 = ((const float4*)rsrc)[q];
            row[4 * q]     = t4.x;
            row[4 * q + 1] = t4.y;
            row[4 * q + 2] = t4.z;
            row[4 * q + 3] = t4.w;
        }
    }
    // pin each element into a VGPR: value becomes opaque -> no remat-from-global
    #pragma unroll
    for (int k = 0; k < 64; ++k) asm volatile("" : "+v"(row[k]));

    const float bias = (h >= 0) ? enc_b[h] : 0.f;
    const float bi   = (tid < 64) ? Bv[tid] : 0.f;

    float s_cur = 0.f;                      // producer: lane tid holds state[tid]

    // producer: build chunk j into st[sel]; state crosses lanes via readlane
    auto build_chunk = [&](int j, int sel) {
        float* dst = st[sel];
        const float* xc = xb + j * CS;
        for (int q = 0; q < CS; ++q) {
            float acc = 0.f;
            #pragma unroll
            for (int k = 0; k < 64; ++k) {
                const float sk = __int_as_float(
                    __builtin_amdgcn_readlane(__float_as_int(s_cur), k));
                acc = fmaf(row[k], sk, acc);         // k-sequential FMA chain
            }
            const float ns = __fadd_rn(acc, __fmul_rn(bi, xc[q]));
            dst[q * 64 + tid] = ns;
            s_cur = ns;
        }
    };

    float mem = 0.f, cnt = 0.f;
    // consumer: LIF over chunk j; 2-timestep ILP, direct LDS float4 broadcast reads
    auto consume_chunk = [&](int j, int sel) {
        const float* src = st[sel];
        float* o = out1 + ((size_t)b * TT + (size_t)j * CS) * HH + h;
        for (int t = 0; t < CS; t += 2) {
            const float4* p0 = (const float4*)(src + t * 64);
            const float4* p1 = (const float4*)(src + t * 64 + 64);
            float acc0 = 0.f, acc1 = 0.f;
            #pragma unroll
            for (int q = 0; q < 16; ++q) {          // two independent chains, interleaved
                const float4 v0 = p0[q];
                const float4 v1 = p1[q];
                acc0 = fmaf(row[4 * q],     v0.x, acc0);
                acc1 = fmaf(row[4 * q],     v1.x, acc1);
                acc0 = fmaf(row[4 * q + 1], v0.y, acc0);
                acc1 = fmaf(row[4 * q + 1], v1.y, acc1);
                acc0 = fmaf(row[4 * q + 2], v0.z, acc0);
                acc1 = fmaf(row[4 * q + 2], v1.z, acc1);
                acc0 = fmaf(row[4 * q + 3], v0.w, acc0);
                acc1 = fmaf(row[4 * q + 3], v1.w, acc1);
            }
            // LIF step t
            float cur = __fadd_rn(acc0, bias);
            mem = __fadd_rn(__fmul_rn(0.9f, mem), cur);
            float sv = (mem > 1.0f) ? 1.0f : 0.0f;
            o[(size_t)t * HH] = sv;
            mem = __fmul_rn(mem, __fsub_rn(1.0f, sv));   // inf*0=NaN as reference
            cnt += sv;
            // LIF step t+1
            cur = __fadd_rn(acc1, bias);
            mem = __fadd_rn(__fmul_rn(0.9f, mem), cur);
            sv = (mem > 1.0f) ? 1.0f : 0.0f;
            o[(size_t)(t + 1) * HH] = sv;
            mem = __fmul_rn(mem, __fsub_rn(1.0f, sv));
            cnt += sv;
        }
    };

    // ---- pipeline: producer one chunk ahead ----
    if (tid < 64) build_chunk(0, 0);
    __syncthreads();
    for (int j = 0; j < NC; ++j) {
        if (tid < 64) {
            if (j + 1 < NC) build_chunk(j + 1, (j + 1) & 1);
        } else {
            consume_chunk(j, j & 1);
        }
        __syncthreads();
    }

    // ---- rate + readout ----
    if (h >= 0) rate[h] = cnt * (1.0f / 4096.0f);   // exact (integer cnt, pow2 divide)
    __syncthreads();
    if (tid < 10) {
        float acc = 0.f;
        for (int k = 0; k < HH; ++k) acc = fmaf(ro_w[tid * HH + k], rate[k], acc);
        out0[b * 10 + tid] = __fadd_rn(acc, ro_b[tid]);
    }
}

extern "C" void kernel_launch(void* const* d_in, const int* in_sizes, int n_in,
                              void* d_out, int out_size, void* d_ws, size_t ws_size,
                              hipStream_t stream) {
    (void)out_size; (void)d_ws; (void)ws_size;
    // size-based input mapping (all seven sizes unique)
    // x:1048576  enc_w:12288  enc_b:192  ro_w:1920  ro_b:10  A:4096  B:64
    const void* px = nullptr; const void* pew = nullptr; const void* peb = nullptr;
    const void* prw = nullptr; const void* prb = nullptr; const void* pA = nullptr;
    const void* pB = nullptr;
    for (int i = 0; i < n_in; ++i) {
        switch (in_sizes[i]) {
            case 1048576: px  = d_in[i]; break;
            case 12288:   pew = d_in[i]; break;
            case 192:     peb = d_in[i]; break;
            case 1920:    prw = d_in[i]; break;
            case 10:      prb = d_in[i]; break;
            case 4096:    pA  = d_in[i]; break;
            case 64:      pB  = d_in[i]; break;
            default: break;
        }
    }
    if (!px || !pew || !peb || !prw || !prb || !pA || !pB) {
        px = d_in[0]; pew = d_in[1]; peb = d_in[2];
        prw = d_in[3]; prb = d_in[4]; pA = d_in[5]; pB = d_in[6];
    }
    const float* x     = (const float*)px;
    const float* enc_w = (const float*)pew;
    const float* enc_b = (const float*)peb;
    const float* ro_w  = (const float*)prw;
    const float* ro_b  = (const float*)prb;
    const float* A     = (const float*)pA;
    const float* Bv    = (const float*)pB;
    float* out0 = (float*)d_out;
    float* out1 = out0 + NBATCH * 10;

    lsnn_fused<<<NBATCH, 256, 0, stream>>>(x, A, Bv, enc_w, enc_b, ro_w, ro_b, out0, out1);
}

// Round 8
// 2000.812 us; speedup vs baseline: 1.0004x; 1.0004x over previous
//
#include <hip/hip_runtime.h>

// StructuredLSNN v8: kill the scratch array — row coefficients in 16 NAMED float4s.
// v7 post-mortem: VGPR_Count=68 proves row[64] was never in registers; it sat in
// scratch and every chain-FMA reloaded its coefficient (L1/L2 latency in the
// dependent chain -> ~1200 cyc/step). The per-element asm pin made the array
// addressable and cemented the scratch allocation. Fix: no arrays, no lambdas —
// named registers w0..w15 (float4) + fully macro-expanded chains.
// Bit-exact op orders preserved from the absmax=0 kernel:
//   k-sequential single-acc fmaf chains; ns = fadd(acc, fmul(bi,u));
//   mem = fadd(fmul(0.9,mem),cur) two-rounded; spike = mem>1; mem *= (1-spk).

#define TT 4096
#define NBATCH 256
#define HH 192
#define CS 64
#define NC (TT / CS)

#define RL(K) __int_as_float(__builtin_amdgcn_readlane(__float_as_int(s_cur), K))

#define PROD_FMA(Q, K0) \
    acc = fmaf(w##Q.x, RL(K0 + 0), acc); \
    acc = fmaf(w##Q.y, RL(K0 + 1), acc); \
    acc = fmaf(w##Q.z, RL(K0 + 2), acc); \
    acc = fmaf(w##Q.w, RL(K0 + 3), acc);

#define CONS_FMA(Q) { \
    const float4 v0 = p0[Q]; \
    const float4 v1 = p1[Q]; \
    acc0 = fmaf(w##Q.x, v0.x, acc0); acc1 = fmaf(w##Q.x, v1.x, acc1); \
    acc0 = fmaf(w##Q.y, v0.y, acc0); acc1 = fmaf(w##Q.y, v1.y, acc1); \
    acc0 = fmaf(w##Q.z, v0.z, acc0); acc1 = fmaf(w##Q.z, v1.z, acc1); \
    acc0 = fmaf(w##Q.w, v0.w, acc0); acc1 = fmaf(w##Q.w, v1.w, acc1); }

#define BUILD_CHUNK(JJ, SEL) { \
    float* dst = st[SEL]; \
    const float* xc = xb + (JJ) * CS; \
    for (int q = 0; q < CS; ++q) { \
        float acc = 0.f; \
        PROD_FMA(0, 0)   PROD_FMA(1, 4)   PROD_FMA(2, 8)   PROD_FMA(3, 12) \
        PROD_FMA(4, 16)  PROD_FMA(5, 20)  PROD_FMA(6, 24)  PROD_FMA(7, 28) \
        PROD_FMA(8, 32)  PROD_FMA(9, 36)  PROD_FMA(10, 40) PROD_FMA(11, 44) \
        PROD_FMA(12, 48) PROD_FMA(13, 52) PROD_FMA(14, 56) PROD_FMA(15, 60) \
        const float ns = __fadd_rn(acc, __fmul_rn(bi, xc[q])); \
        dst[q * 64 + tid] = ns; \
        s_cur = ns; \
    } }

#define LIF_STEP(ACC, TOFF) { \
    const float cur = __fadd_rn(ACC, bias); \
    mem = __fadd_rn(__fmul_rn(0.9f, mem), cur); \
    const float sv = (mem > 1.0f) ? 1.0f : 0.0f; \
    o[(size_t)(t + TOFF) * HH] = sv; \
    mem = __fmul_rn(mem, __fsub_rn(1.0f, sv)); \
    cnt += sv; }

#define CONSUME_CHUNK(JJ, SEL) { \
    const float* src = st[SEL]; \
    float* o = out1 + ((size_t)b * TT + (size_t)(JJ) * CS) * HH + h; \
    for (int t = 0; t < CS; t += 2) { \
        const float4* p0 = (const float4*)(src + t * 64); \
        const float4* p1 = (const float4*)(src + t * 64 + 64); \
        float acc0 = 0.f, acc1 = 0.f; \
        CONS_FMA(0)  CONS_FMA(1)  CONS_FMA(2)  CONS_FMA(3) \
        CONS_FMA(4)  CONS_FMA(5)  CONS_FMA(6)  CONS_FMA(7) \
        CONS_FMA(8)  CONS_FMA(9)  CONS_FMA(10) CONS_FMA(11) \
        CONS_FMA(12) CONS_FMA(13) CONS_FMA(14) CONS_FMA(15) \
        LIF_STEP(acc0, 0) \
        LIF_STEP(acc1, 1) \
    } }

__global__ __launch_bounds__(256, 1) void lsnn_fused(
    const float* __restrict__ x,
    const float* __restrict__ A,
    const float* __restrict__ Bv,
    const float* __restrict__ enc_w,
    const float* __restrict__ enc_b,
    const float* __restrict__ ro_w,
    const float* __restrict__ ro_b,
    float* __restrict__ out0,
    float* __restrict__ out1)
{
    __shared__ __align__(16) float st[2][CS * 64];   // chunk state tiles [q][d]
    __shared__ __align__(16) float xb[TT];           // this batch's input
    __shared__ float rate[HH];

    const int tid = threadIdx.x;
    const int b = blockIdx.x;
    const int h = tid - 64;                 // consumer lane id 0..191 (tid>=64)

    // ---- stage x[b][:] ----
    {
        const float4* xs = (const float4*)(x + (size_t)b * TT);
        float4* xd = (float4*)xb;
        for (int e = tid; e < TT / 4; e += 256) xd[e] = xs[e];
    }

    // ---- row coefficients in 16 NAMED float4 registers ----
    const float4* r4 = (tid < 64) ? (const float4*)(A + (size_t)tid * 64)
                                  : (const float4*)(enc_w + (size_t)h * 64);
    float4 w0 = r4[0],   w1 = r4[1],   w2 = r4[2],   w3 = r4[3];
    float4 w4 = r4[4],   w5 = r4[5],   w6 = r4[6],   w7 = r4[7];
    float4 w8 = r4[8],   w9 = r4[9],   w10 = r4[10], w11 = r4[11];
    float4 w12 = r4[12], w13 = r4[13], w14 = r4[14], w15 = r4[15];

    const float bias = (h >= 0) ? enc_b[h] : 0.f;
    const float bi   = (tid < 64) ? Bv[tid] : 0.f;

    float s_cur = 0.f;                      // producer: lane tid holds state[tid]
    float mem = 0.f, cnt = 0.f;

    // ---- pipeline: producer one chunk ahead ----
    if (tid < 64) BUILD_CHUNK(0, 0)
    __syncthreads();
    for (int j = 0; j < NC; ++j) {
        if (tid < 64) {
            if (j + 1 < NC) BUILD_CHUNK(j + 1, (j + 1) & 1)
        } else {
            CONSUME_CHUNK(j, j & 1)
        }
        __syncthreads();
    }

    // ---- rate + readout ----
    if (h >= 0) rate[h] = cnt * (1.0f / 4096.0f);   // exact (integer cnt, pow2 divide)
    __syncthreads();
    if (tid < 10) {
        float acc = 0.f;
        for (int k = 0; k < HH; ++k) acc = fmaf(ro_w[tid * HH + k], rate[k], acc);
        out0[b * 10 + tid] = __fadd_rn(acc, ro_b[tid]);
    }
}

extern "C" void kernel_launch(void* const* d_in, const int* in_sizes, int n_in,
                              void* d_out, int out_size, void* d_ws, size_t ws_size,
                              hipStream_t stream) {
    (void)out_size; (void)d_ws; (void)ws_size;
    // size-based input mapping (all seven sizes unique)
    // x:1048576  enc_w:12288  enc_b:192  ro_w:1920  ro_b:10  A:4096  B:64
    const void* px = nullptr; const void* pew = nullptr; const void* peb = nullptr;
    const void* prw = nullptr; const void* prb = nullptr; const void* pA = nullptr;
    const void* pB = nullptr;
    for (int i = 0; i < n_in; ++i) {
        switch (in_sizes[i]) {
            case 1048576: px  = d_in[i]; break;
            case 12288:   pew = d_in[i]; break;
            case 192:     peb = d_in[i]; break;
            case 1920:    prw = d_in[i]; break;
            case 10:      prb = d_in[i]; break;
            case 4096:    pA  = d_in[i]; break;
            case 64:      pB  = d_in[i]; break;
            default: break;
        }
    }
    if (!px || !pew || !peb || !prw || !prb || !pA || !pB) {
        px = d_in[0]; pew = d_in[1]; peb = d_in[2];
        prw = d_in[3]; prb = d_in[4]; pA = d_in[5]; pB = d_in[6];
    }
    const float* x     = (const float*)px;
    const float* enc_w = (const float*)pew;
    const float* enc_b = (const float*)peb;
    const float* ro_w  = (const float*)prw;
    const float* ro_b  = (const float*)prb;
    const float* A     = (const float*)pA;
    const float* Bv    = (const float*)pB;
    float* out0 = (float*)d_out;
    float* out1 = out0 + NBATCH * 10;

    lsnn_fused<<<NBATCH, 256, 0, stream>>>(x, A, Bv, enc_w, enc_b, ro_w, ro_b, out0, out1);
}

// Round 9
// 1219.672 us; speedup vs baseline: 1.6411x; 1.6405x over previous
//
#include <hip/hip_runtime.h>

// StructuredLSNN v9: hoist streamed operands out of the dependence chains.
// v8 post-mortem: VGPR=68 == 64 weights + 4 temps -> weights WERE in registers
// all along; the ~1190 cyc/step constant across v5-v8 is per-quantum operand
// fetch INSIDE the chains (readlane->SGPR-hazard per k in producer; unhoisted
// ~120cyc ds_read latency per float4 in consumer).
// Fix: producer = 64 named readlane scalars BEFORE the 64-FMA chain;
//      consumer = 32 named float4 LDS loads BEFORE the dual 128-FMA chain.
// Bit-exact op orders preserved (k-sequential single-acc fmaf chains,
// two-rounded LIF update, NaN-propagating mem*(1-spk) reset).

#define TT 4096
#define NBATCH 256
#define HH 192
#define CS 64
#define NC (TT / CS)

// ---- producer: hoisted readlane scalars ----
#define RL1(K) const float sreg##K = __int_as_float( \
    __builtin_amdgcn_readlane(__float_as_int(s_cur), K));
#define RL4(A,B,C,D) RL1(A) RL1(B) RL1(C) RL1(D)

#define PFMA(Q, K0, K1, K2, K3) \
    acc = fmaf(w##Q.x, sreg##K0, acc); \
    acc = fmaf(w##Q.y, sreg##K1, acc); \
    acc = fmaf(w##Q.z, sreg##K2, acc); \
    acc = fmaf(w##Q.w, sreg##K3, acc);

#define BUILD_CHUNK(JJ, SEL) { \
    float* dst = st[SEL]; \
    const float* xc = xb + (JJ) * CS; \
    for (int q = 0; q < CS; ++q) { \
        RL4(0,1,2,3)     RL4(4,5,6,7)     RL4(8,9,10,11)   RL4(12,13,14,15) \
        RL4(16,17,18,19) RL4(20,21,22,23) RL4(24,25,26,27) RL4(28,29,30,31) \
        RL4(32,33,34,35) RL4(36,37,38,39) RL4(40,41,42,43) RL4(44,45,46,47) \
        RL4(48,49,50,51) RL4(52,53,54,55) RL4(56,57,58,59) RL4(60,61,62,63) \
        float acc = 0.f; \
        PFMA(0, 0,1,2,3)     PFMA(1, 4,5,6,7)     PFMA(2, 8,9,10,11) \
        PFMA(3, 12,13,14,15) PFMA(4, 16,17,18,19) PFMA(5, 20,21,22,23) \
        PFMA(6, 24,25,26,27) PFMA(7, 28,29,30,31) PFMA(8, 32,33,34,35) \
        PFMA(9, 36,37,38,39) PFMA(10,40,41,42,43) PFMA(11,44,45,46,47) \
        PFMA(12,48,49,50,51) PFMA(13,52,53,54,55) PFMA(14,56,57,58,59) \
        PFMA(15,60,61,62,63) \
        const float ns = __fadd_rn(acc, __fmul_rn(bi, xc[q])); \
        dst[q * 64 + tid] = ns; \
        s_cur = ns; \
    } }

// ---- consumer: hoisted LDS float4 loads, dual interleaved chains ----
#define CLD(Q) const float4 va##Q = p0[Q]; const float4 vb##Q = p1[Q];

#define CFMA(Q) \
    acc0 = fmaf(w##Q.x, va##Q.x, acc0); acc1 = fmaf(w##Q.x, vb##Q.x, acc1); \
    acc0 = fmaf(w##Q.y, va##Q.y, acc0); acc1 = fmaf(w##Q.y, vb##Q.y, acc1); \
    acc0 = fmaf(w##Q.z, va##Q.z, acc0); acc1 = fmaf(w##Q.z, vb##Q.z, acc1); \
    acc0 = fmaf(w##Q.w, va##Q.w, acc0); acc1 = fmaf(w##Q.w, vb##Q.w, acc1);

#define LIF_STEP(ACC, TOFF) { \
    const float cur = __fadd_rn(ACC, bias); \
    mem = __fadd_rn(__fmul_rn(0.9f, mem), cur); \
    const float sv = (mem > 1.0f) ? 1.0f : 0.0f; \
    o[(size_t)(t + TOFF) * HH] = sv; \
    mem = __fmul_rn(mem, __fsub_rn(1.0f, sv)); \
    cnt += sv; }

#define CONSUME_CHUNK(JJ, SEL) { \
    const float* src = st[SEL]; \
    float* o = out1 + ((size_t)b * TT + (size_t)(JJ) * CS) * HH + h; \
    for (int t = 0; t < CS; t += 2) { \
        const float4* p0 = (const float4*)(src + t * 64); \
        const float4* p1 = (const float4*)(src + t * 64 + 64); \
        CLD(0)  CLD(1)  CLD(2)  CLD(3)  CLD(4)  CLD(5)  CLD(6)  CLD(7) \
        CLD(8)  CLD(9)  CLD(10) CLD(11) CLD(12) CLD(13) CLD(14) CLD(15) \
        float acc0 = 0.f, acc1 = 0.f; \
        CFMA(0)  CFMA(1)  CFMA(2)  CFMA(3)  CFMA(4)  CFMA(5)  CFMA(6)  CFMA(7) \
        CFMA(8)  CFMA(9)  CFMA(10) CFMA(11) CFMA(12) CFMA(13) CFMA(14) CFMA(15) \
        LIF_STEP(acc0, 0) \
        LIF_STEP(acc1, 1) \
    } }

__global__ __launch_bounds__(256, 1) void lsnn_fused(
    const float* __restrict__ x,
    const float* __restrict__ A,
    const float* __restrict__ Bv,
    const float* __restrict__ enc_w,
    const float* __restrict__ enc_b,
    const float* __restrict__ ro_w,
    const float* __restrict__ ro_b,
    float* __restrict__ out0,
    float* __restrict__ out1)
{
    __shared__ __align__(16) float st[2][CS * 64];   // chunk state tiles [q][d]
    __shared__ __align__(16) float xb[TT];           // this batch's input
    __shared__ float rate[HH];

    const int tid = threadIdx.x;
    const int b = blockIdx.x;
    const int h = tid - 64;                 // consumer lane id 0..191 (tid>=64)

    // ---- stage x[b][:] ----
    {
        const float4* xs = (const float4*)(x + (size_t)b * TT);
        float4* xd = (float4*)xb;
        for (int e = tid; e < TT / 4; e += 256) xd[e] = xs[e];
    }

    // ---- row coefficients in 16 named float4 registers ----
    const float4* r4 = (tid < 64) ? (const float4*)(A + (size_t)tid * 64)
                                  : (const float4*)(enc_w + (size_t)h * 64);
    float4 w0 = r4[0],   w1 = r4[1],   w2 = r4[2],   w3 = r4[3];
    float4 w4 = r4[4],   w5 = r4[5],   w6 = r4[6],   w7 = r4[7];
    float4 w8 = r4[8],   w9 = r4[9],   w10 = r4[10], w11 = r4[11];
    float4 w12 = r4[12], w13 = r4[13], w14 = r4[14], w15 = r4[15];

    const float bias = (h >= 0) ? enc_b[h] : 0.f;
    const float bi   = (tid < 64) ? Bv[tid] : 0.f;

    float s_cur = 0.f;                      // producer: lane tid holds state[tid]
    float mem = 0.f, cnt = 0.f;

    // ---- pipeline: producer one chunk ahead ----
    if (tid < 64) BUILD_CHUNK(0, 0)
    __syncthreads();
    for (int j = 0; j < NC; ++j) {
        if (tid < 64) {
            if (j + 1 < NC) BUILD_CHUNK(j + 1, (j + 1) & 1)
        } else {
            CONSUME_CHUNK(j, j & 1)
        }
        __syncthreads();
    }

    // ---- rate + readout ----
    if (h >= 0) rate[h] = cnt * (1.0f / 4096.0f);   // exact (integer cnt, pow2 divide)
    __syncthreads();
    if (tid < 10) {
        float acc = 0.f;
        for (int k = 0; k < HH; ++k) acc = fmaf(ro_w[tid * HH + k], rate[k], acc);
        out0[b * 10 + tid] = __fadd_rn(acc, ro_b[tid]);
    }
}

extern "C" void kernel_launch(void* const* d_in, const int* in_sizes, int n_in,
                              void* d_out, int out_size, void* d_ws, size_t ws_size,
                              hipStream_t stream) {
    (void)out_size; (void)d_ws; (void)ws_size;
    // size-based input mapping (all seven sizes unique)
    // x:1048576  enc_w:12288  enc_b:192  ro_w:1920  ro_b:10  A:4096  B:64
    const void* px = nullptr; const void* pew = nullptr; const void* peb = nullptr;
    const void* prw = nullptr; const void* prb = nullptr; const void* pA = nullptr;
    const void* pB = nullptr;
    for (int i = 0; i < n_in; ++i) {
        switch (in_sizes[i]) {
            case 1048576: px  = d_in[i]; break;
            case 12288:   pew = d_in[i]; break;
            case 192:     peb = d_in[i]; break;
            case 1920:    prw = d_in[i]; break;
            case 10:      prb = d_in[i]; break;
            case 4096:    pA  = d_in[i]; break;
            case 64:      pB  = d_in[i]; break;
            default: break;
        }
    }
    if (!px || !pew || !peb || !prw || !prb || !pA || !pB) {
        px = d_in[0]; pew = d_in[1]; peb = d_in[2];
        prw = d_in[3]; prb = d_in[4]; pA = d_in[5]; pB = d_in[6];
    }
    const float* x     = (const float*)px;
    const float* enc_w = (const float*)pew;
    const float* enc_b = (const float*)peb;
    const float* ro_w  = (const float*)prw;
    const float* ro_b  = (const float*)prb;
    const float* A     = (const float*)pA;
    const float* Bv    = (const float*)pB;
    float* out0 = (float*)d_out;
    float* out1 = out0 + NBATCH * 10;

    lsnn_fused<<<NBATCH, 256, 0, stream>>>(x, A, Bv, enc_w, enc_b, ro_w, ro_b, out0, out1);
}

// Round 10
// 1106.524 us; speedup vs baseline: 1.8089x; 1.1023x over previous
//
#include <hip/hip_runtime.h>

// StructuredLSNN v10: consumer operands via readlane, not broadcast LDS reads.
// v9 post-mortem (1220us, 715 cyc/step): consumer's 16 broadcast ds_read_b128
// per step x 3 waves = 48 LDS-pipe instrs/step @~12cyc = ~576 cyc/step gated
// the kernel (producer ~390). All 3 consumer waves re-read the SAME tile.
// Fix: per step each consumer wave does ONE ds_read_b128 (lane L holds quad
// L&15 of state[t]); the 64 scalars are extracted with v_readlane (VALU issue,
// no LDS pipe, no memory latency) in two 64-scalar half-batches feeding the
// dual interleaved FMA chains. Per-chain k-order unchanged -> bit-exact.
// Producer unchanged from v9 (hoisted 64 readlanes + 64-FMA chain).

#define TT 4096
#define NBATCH 256
#define HH 192
#define CS 64
#define NC (TT / CS)

// ---- producer: hoisted readlane scalars ----
#define RL1(K) const float sreg##K = __int_as_float( \
    __builtin_amdgcn_readlane(__float_as_int(s_cur), K));
#define RL4(A,B,C,D) RL1(A) RL1(B) RL1(C) RL1(D)

#define PFMA(Q, K0, K1, K2, K3) \
    acc = fmaf(w##Q.x, sreg##K0, acc); \
    acc = fmaf(w##Q.y, sreg##K1, acc); \
    acc = fmaf(w##Q.z, sreg##K2, acc); \
    acc = fmaf(w##Q.w, sreg##K3, acc);

#define BUILD_CHUNK(JJ, SEL) { \
    float* dst = st[SEL]; \
    const float* xc = xb + (JJ) * CS; \
    for (int q = 0; q < CS; ++q) { \
        RL4(0,1,2,3)     RL4(4,5,6,7)     RL4(8,9,10,11)   RL4(12,13,14,15) \
        RL4(16,17,18,19) RL4(20,21,22,23) RL4(24,25,26,27) RL4(28,29,30,31) \
        RL4(32,33,34,35) RL4(36,37,38,39) RL4(40,41,42,43) RL4(44,45,46,47) \
        RL4(48,49,50,51) RL4(52,53,54,55) RL4(56,57,58,59) RL4(60,61,62,63) \
        float acc = 0.f; \
        PFMA(0, 0,1,2,3)     PFMA(1, 4,5,6,7)     PFMA(2, 8,9,10,11) \
        PFMA(3, 12,13,14,15) PFMA(4, 16,17,18,19) PFMA(5, 20,21,22,23) \
        PFMA(6, 24,25,26,27) PFMA(7, 28,29,30,31) PFMA(8, 32,33,34,35) \
        PFMA(9, 36,37,38,39) PFMA(10,40,41,42,43) PFMA(11,44,45,46,47) \
        PFMA(12,48,49,50,51) PFMA(13,52,53,54,55) PFMA(14,56,57,58,59) \
        PFMA(15,60,61,62,63) \
        const float ns = __fadd_rn(acc, __fmul_rn(bi, xc[q])); \
        dst[q * 64 + tid] = ns; \
        s_cur = ns; \
    } }

// ---- consumer: readlane extraction from one b128/step ----
// va holds quad (tid&15) of state[t]: component c of lane q == state[t][4q+c].
#define XRL(V, Q) __int_as_float(__builtin_amdgcn_readlane(__float_as_int(V), Q))

#define CRLQ(Q) \
    const float sa##Q##0 = XRL(va.x, Q); const float sb##Q##0 = XRL(vb.x, Q); \
    const float sa##Q##1 = XRL(va.y, Q); const float sb##Q##1 = XRL(vb.y, Q); \
    const float sa##Q##2 = XRL(va.z, Q); const float sb##Q##2 = XRL(vb.z, Q); \
    const float sa##Q##3 = XRL(va.w, Q); const float sb##Q##3 = XRL(vb.w, Q);

#define CFQ(Q) \
    acc0 = fmaf(w##Q.x, sa##Q##0, acc0); acc1 = fmaf(w##Q.x, sb##Q##0, acc1); \
    acc0 = fmaf(w##Q.y, sa##Q##1, acc0); acc1 = fmaf(w##Q.y, sb##Q##1, acc1); \
    acc0 = fmaf(w##Q.z, sa##Q##2, acc0); acc1 = fmaf(w##Q.z, sb##Q##2, acc1); \
    acc0 = fmaf(w##Q.w, sa##Q##3, acc0); acc1 = fmaf(w##Q.w, sb##Q##3, acc1);

#define LIF_STEP(ACC, TOFF) { \
    const float cur = __fadd_rn(ACC, bias); \
    mem = __fadd_rn(__fmul_rn(0.9f, mem), cur); \
    const float sv = (mem > 1.0f) ? 1.0f : 0.0f; \
    o[(size_t)(t + TOFF) * HH] = sv; \
    mem = __fmul_rn(mem, __fsub_rn(1.0f, sv)); \
    cnt += sv; }

#define CONSUME_CHUNK(JJ, SEL) { \
    const float* src = st[SEL] + (tid & 15) * 4; \
    float* o = out1 + ((size_t)b * TT + (size_t)(JJ) * CS) * HH + h; \
    for (int t = 0; t < CS; t += 2) { \
        const float4 va = *(const float4*)(src + t * 64); \
        const float4 vb = *(const float4*)(src + t * 64 + 64); \
        float acc0 = 0.f, acc1 = 0.f; \
        CRLQ(0) CRLQ(1) CRLQ(2) CRLQ(3) CRLQ(4) CRLQ(5) CRLQ(6) CRLQ(7) \
        CFQ(0)  CFQ(1)  CFQ(2)  CFQ(3)  CFQ(4)  CFQ(5)  CFQ(6)  CFQ(7) \
        CRLQ(8) CRLQ(9) CRLQ(10) CRLQ(11) CRLQ(12) CRLQ(13) CRLQ(14) CRLQ(15) \
        CFQ(8)  CFQ(9)  CFQ(10)  CFQ(11)  CFQ(12)  CFQ(13)  CFQ(14)  CFQ(15) \
        LIF_STEP(acc0, 0) \
        LIF_STEP(acc1, 1) \
    } }

__global__ __launch_bounds__(256, 1) void lsnn_fused(
    const float* __restrict__ x,
    const float* __restrict__ A,
    const float* __restrict__ Bv,
    const float* __restrict__ enc_w,
    const float* __restrict__ enc_b,
    const float* __restrict__ ro_w,
    const float* __restrict__ ro_b,
    float* __restrict__ out0,
    float* __restrict__ out1)
{
    __shared__ __align__(16) float st[2][CS * 64];   // chunk state tiles [q][d]
    __shared__ __align__(16) float xb[TT];           // this batch's input
    __shared__ float rate[HH];

    const int tid = threadIdx.x;
    const int b = blockIdx.x;
    const int h = tid - 64;                 // consumer lane id 0..191 (tid>=64)

    // ---- stage x[b][:] ----
    {
        const float4* xs = (const float4*)(x + (size_t)b * TT);
        float4* xd = (float4*)xb;
        for (int e = tid; e < TT / 4; e += 256) xd[e] = xs[e];
    }

    // ---- row coefficients in 16 named float4 registers ----
    const float4* r4 = (tid < 64) ? (const float4*)(A + (size_t)tid * 64)
                                  : (const float4*)(enc_w + (size_t)h * 64);
    float4 w0 = r4[0],   w1 = r4[1],   w2 = r4[2],   w3 = r4[3];
    float4 w4 = r4[4],   w5 = r4[5],   w6 = r4[6],   w7 = r4[7];
    float4 w8 = r4[8],   w9 = r4[9],   w10 = r4[10], w11 = r4[11];
    float4 w12 = r4[12], w13 = r4[13], w14 = r4[14], w15 = r4[15];

    const float bias = (h >= 0) ? enc_b[h] : 0.f;
    const float bi   = (tid < 64) ? Bv[tid] : 0.f;

    float s_cur = 0.f;                      // producer: lane tid holds state[tid]
    float mem = 0.f, cnt = 0.f;

    // ---- pipeline: producer one chunk ahead ----
    if (tid < 64) BUILD_CHUNK(0, 0)
    __syncthreads();
    for (int j = 0; j < NC; ++j) {
        if (tid < 64) {
            if (j + 1 < NC) BUILD_CHUNK(j + 1, (j + 1) & 1)
        } else {
            CONSUME_CHUNK(j, j & 1)
        }
        __syncthreads();
    }

    // ---- rate + readout ----
    if (h >= 0) rate[h] = cnt * (1.0f / 4096.0f);   // exact (integer cnt, pow2 divide)
    __syncthreads();
    if (tid < 10) {
        float acc = 0.f;
        for (int k = 0; k < HH; ++k) acc = fmaf(ro_w[tid * HH + k], rate[k], acc);
        out0[b * 10 + tid] = __fadd_rn(acc, ro_b[tid]);
    }
}

extern "C" void kernel_launch(void* const* d_in, const int* in_sizes, int n_in,
                              void* d_out, int out_size, void* d_ws, size_t ws_size,
                              hipStream_t stream) {
    (void)out_size; (void)d_ws; (void)ws_size;
    // size-based input mapping (all seven sizes unique)
    // x:1048576  enc_w:12288  enc_b:192  ro_w:1920  ro_b:10  A:4096  B:64
    const void* px = nullptr; const void* pew = nullptr; const void* peb = nullptr;
    const void* prw = nullptr; const void* prb = nullptr; const void* pA = nullptr;
    const void* pB = nullptr;
    for (int i = 0; i < n_in; ++i) {
        switch (in_sizes[i]) {
            case 1048576: px  = d_in[i]; break;
            case 12288:   pew = d_in[i]; break;
            case 192:     peb = d_in[i]; break;
            case 1920:    prw = d_in[i]; break;
            case 10:      prb = d_in[i]; break;
            case 4096:    pA  = d_in[i]; break;
            case 64:      pB  = d_in[i]; break;
            default: break;
        }
    }
    if (!px || !pew || !peb || !prw || !prb || !pA || !pB) {
        px = d_in[0]; pew = d_in[1]; peb = d_in[2];
        prw = d_in[3]; prb = d_in[4]; pA = d_in[5]; pB = d_in[6];
    }
    const float* x     = (const float*)px;
    const float* enc_w = (const float*)pew;
    const float* enc_b = (const float*)peb;
    const float* ro_w  = (const float*)prw;
    const float* ro_b  = (const float*)prb;
    const float* A     = (const float*)pA;
    const float* Bv    = (const float*)pB;
    float* out0 = (float*)d_out;
    float* out1 = out0 + NBATCH * 10;

    lsnn_fused<<<NBATCH, 256, 0, stream>>>(x, A, Bv, enc_w, enc_b, ro_w, ro_b, out0, out1);
}